// Round 1
// baseline (1258.759 us; speedup 1.0000x reference)
//
#include <hip/hip_runtime.h>
#include <math.h>

// Problem constants (from reference: B=4, S=1024, D=512, COMP=4)
#define S 1024
#define D 512
#define NCOMP (S / 4)        // 256
#define STEPS (S - NCOMP)    // 768
#define NEG_INF (-__builtin_inff())

// Butterfly sum across the 64-lane wave; every lane ends with the total.
__device__ __forceinline__ float wave_sum(float acc) {
#pragma unroll
    for (int off = 1; off < 64; off <<= 1) acc += __shfl_xor(acc, off, 64);
    return acc;
}

// Dot of two rows where each lane holds 8 contiguous floats (2x float4).
// Fixed accumulation order so init and incremental updates are consistent.
__device__ __forceinline__ float dot8(float4 a0, float4 a1, float4 b0, float4 b1) {
    float acc = a0.x * b0.x;
    acc += a0.y * b0.y; acc += a0.z * b0.z; acc += a0.w * b0.w;
    acc += a1.x * b1.x; acc += a1.y * b1.y; acc += a1.z * b1.z; acc += a1.w * b1.w;
    return wave_sum(acc);
}

__global__ __launch_bounds__(1024) void pool_merge_kernel(
    const float* __restrict__ x, float* __restrict__ out, float* vals_base) {
    const int b    = blockIdx.x;
    const int tid  = threadIdx.x;
    const int lane = tid & 63;
    const int wave = tid >> 6;       // 16 waves
    const int NW   = blockDim.x >> 6;

    float* vals = vals_base + (size_t)b * S * D;
    const float* xin = x + (size_t)b * S * D;

    __shared__ float dist[S];   // dist[s] = dot(vals[s], vals[next(s)]); -inf if last/removed
    __shared__ int   nxt[S];    // doubly linked list over active slots
    __shared__ int   prv[S];
    __shared__ int   outIdx[NCOMP];

    // ---- init: copy sample into workspace (skip if operating in place) ----
    if (vals != (float*)xin) {
        const float4* s4 = (const float4*)xin;
        float4* d4 = (float4*)vals;
        for (int i = tid; i < S * D / 4; i += blockDim.x) d4[i] = s4[i];
    }
    for (int s = tid; s < S; s += blockDim.x) { nxt[s] = s + 1; prv[s] = s - 1; }
    __syncthreads();

    // ---- init: 1023 adjacent-pair dots, one wave per pair ----
    for (int p = wave; p < S - 1; p += NW) {
        const float4* a4 = (const float4*)(vals + (size_t)p * D);
        const float4* b4 = (const float4*)(vals + (size_t)(p + 1) * D);
        float4 a0 = a4[lane * 2], a1 = a4[lane * 2 + 1];
        float4 b0 = b4[lane * 2], b1 = b4[lane * 2 + 1];
        float dd = dot8(a0, a1, b0, b1);
        if (lane == 0) dist[p] = dd;
    }
    if (tid == 0) dist[S - 1] = NEG_INF;  // last token never has a valid pair
    __syncthreads();

    // ---- main loop: wave 0 only, no barriers (lockstep within the wave) ----
    if (wave == 0) {
        for (int t = 0; t < STEPS; ++t) {
            // argmax over dist[0..S-1], ties -> smallest slot index
            float v = dist[lane];
            int bi = lane;
#pragma unroll
            for (int k = 1; k < 16; ++k) {
                int s = lane + 64 * k;          // conflict-free LDS layout
                float dv = dist[s];
                if (dv > v) { v = dv; bi = s; } // equal keeps smaller s
            }
#pragma unroll
            for (int off = 1; off < 64; off <<= 1) {
                float ov = __shfl_xor(v, off, 64);
                int oi = __shfl_xor(bi, off, 64);
                if (ov > v || (ov == v && oi < bi)) { v = ov; bi = oi; }
            }
            const int m = bi;          // merge pair (m, r); r removed
            const int r = nxt[m];
            const int q = nxt[r];      // new right neighbor of m (S = end sentinel)
            const int p = prv[m];      // left neighbor of m (-1 = none)

            if (lane == 0) {
                nxt[m] = q;
                if (q < S) prv[q] = m;
                dist[r] = NEG_INF;     // slot r is dead
            }

            // load rows (8 floats/lane), average m+r in registers
            const float4* pm = (const float4*)(vals + (size_t)m * D);
            const float4* pr = (const float4*)(vals + (size_t)r * D);
            float4 am0 = pm[lane * 2], am1 = pm[lane * 2 + 1];
            float4 ar0 = pr[lane * 2], ar1 = pr[lane * 2 + 1];
            float4 vp0, vp1, vq0, vq1;
            if (p >= 0) {
                const float4* pp = (const float4*)(vals + (size_t)p * D);
                vp0 = pp[lane * 2]; vp1 = pp[lane * 2 + 1];
            }
            if (q < S) {
                const float4* pq = (const float4*)(vals + (size_t)q * D);
                vq0 = pq[lane * 2]; vq1 = pq[lane * 2 + 1];
            }
            float4 vm0, vm1;
            vm0.x = (am0.x + ar0.x) * 0.5f; vm0.y = (am0.y + ar0.y) * 0.5f;
            vm0.z = (am0.z + ar0.z) * 0.5f; vm0.w = (am0.w + ar0.w) * 0.5f;
            vm1.x = (am1.x + ar1.x) * 0.5f; vm1.y = (am1.y + ar1.y) * 0.5f;
            vm1.z = (am1.z + ar1.z) * 0.5f; vm1.w = (am1.w + ar1.w) * 0.5f;
            ((float4*)(vals + (size_t)m * D))[lane * 2]     = vm0;
            ((float4*)(vals + (size_t)m * D))[lane * 2 + 1] = vm1;

            // only the two dists adjacent to the merge change
            if (p >= 0) {
                float dpm = dot8(vp0, vp1, vm0, vm1);
                if (lane == 0) dist[p] = dpm;
            }
            if (q < S) {
                float dmq = dot8(vm0, vm1, vq0, vq1);
                if (lane == 0) dist[m] = dmq;
            } else if (lane == 0) {
                dist[m] = NEG_INF;
            }
        }
    }
    __syncthreads();

    // ---- output: first NCOMP active slots in order ----
    if (tid == 0) {
        int s = 0;                    // slot 0 is never removed (never a right token)
        for (int i = 0; i < NCOMP; ++i) { outIdx[i] = s; s = nxt[s]; }
    }
    __syncthreads();

    float* outb = out + (size_t)b * NCOMP * D;
    for (int i = wave; i < NCOMP; i += NW) {
        const float4* sr = (const float4*)(vals + (size_t)outIdx[i] * D);
        float4* dr = (float4*)(outb + (size_t)i * D);
        dr[lane * 2]     = sr[lane * 2];
        dr[lane * 2 + 1] = sr[lane * 2 + 1];
    }
}

extern "C" void kernel_launch(void* const* d_in, const int* in_sizes, int n_in,
                              void* d_out, int out_size, void* d_ws, size_t ws_size,
                              hipStream_t stream) {
    const float* x = (const float*)d_in[0];
    float* out = (float*)d_out;
    const int b = in_sizes[0] / (S * D);   // 4
    const size_t need = (size_t)in_sizes[0] * sizeof(float);
    // Prefer scratch; fall back to in-place on the input (harness restores
    // d_in from pristine before every launch, so mutation is safe).
    float* vals = (ws_size >= need) ? (float*)d_ws : (float*)x;
    pool_merge_kernel<<<dim3(b), dim3(1024), 0, stream>>>(x, out, vals);
}

// Round 2
// 1100.288 us; speedup vs baseline: 1.1440x; 1.1440x over previous
//
#include <hip/hip_runtime.h>
#include <math.h>

// Problem constants (from reference: B=4, S=1024, D=512, COMP=4)
#define S 1024
#define D 512
#define NCOMP (S / 4)        // 256
#define STEPS (S - NCOMP)    // 768
#define NW 16                // waves per block (block = 1024)
#define NEG_INF (-__builtin_inff())

__device__ __forceinline__ int   f2i(float x) { return __builtin_bit_cast(int, x); }
__device__ __forceinline__ float i2f(int x)   { return __builtin_bit_cast(float, x); }

// Monotone float->uint key; strictly > 0 for every non-NaN float, so a
// 0-filled DPP lane can never win the max under either bound_ctrl semantic.
__device__ __forceinline__ unsigned fkey(float f) {
    unsigned u = __builtin_bit_cast(unsigned, f);
    return (u & 0x80000000u) ? ~u : (u | 0x80000000u);
}

// Full-wave sum via DPP (row_shr + row_bcast); total lands in lane 63.
// old=0 + bound_ctrl=true -> invalid lanes contribute 0 under either semantic.
__device__ __forceinline__ float wave_sum63(float x) {
    x += i2f(__builtin_amdgcn_update_dpp(0, f2i(x), 0x111, 0xF, 0xF, true)); // shr1
    x += i2f(__builtin_amdgcn_update_dpp(0, f2i(x), 0x112, 0xF, 0xF, true)); // shr2
    x += i2f(__builtin_amdgcn_update_dpp(0, f2i(x), 0x114, 0xF, 0xF, true)); // shr4
    x += i2f(__builtin_amdgcn_update_dpp(0, f2i(x), 0x118, 0xF, 0xF, true)); // shr8
    x += i2f(__builtin_amdgcn_update_dpp(0, f2i(x), 0x142, 0xA, 0xF, true)); // bcast15 -> rows 1,3
    x += i2f(__builtin_amdgcn_update_dpp(0, f2i(x), 0x143, 0xC, 0xF, true)); // bcast31 -> rows 2,3
    return x;  // lane 63 holds the total
}

// One DPP argmax step: move (key,idx) per ctrl, take if strictly greater or
// equal-with-smaller-index. old=own + bound_ctrl=false: no-op under old-keep
// semantics; key 0 (never wins) under 0-fill semantics. Safe either way.
#define AMAX_STEP(ctrl, rm) do {                                                        \
    unsigned ok_ = (unsigned)__builtin_amdgcn_update_dpp((int)key, (int)key, (ctrl), (rm), 0xF, false); \
    int      oi_ = __builtin_amdgcn_update_dpp(bi, bi, (ctrl), (rm), 0xF, false);        \
    bool tk_ = (ok_ > key) || ((ok_ == key) && (oi_ < bi));                              \
    key = tk_ ? ok_ : key; bi = tk_ ? oi_ : bi;                                          \
} while (0)

// Per-lane partial dot over the lane's 8 contiguous floats, fixed order
// (same order everywhere -> init and incremental dists bit-consistent).
__device__ __forceinline__ float dot8_partial(float4 a0, float4 a1, float4 b0, float4 b1) {
    float acc = a0.x * b0.x;
    acc += a0.y * b0.y; acc += a0.z * b0.z; acc += a0.w * b0.w;
    acc += a1.x * b1.x; acc += a1.y * b1.y; acc += a1.z * b1.z; acc += a1.w * b1.w;
    return acc;
}

// Register-resident dist update: k is wave-uniform (sgpr) -> scalar switch,
// one v_cndmask on the matching register.
__device__ __forceinline__ void dist_set(float (&dv)[16], bool ln, int k, float val) {
    switch (k) {
        case 0:  if (ln) dv[0]  = val; break;
        case 1:  if (ln) dv[1]  = val; break;
        case 2:  if (ln) dv[2]  = val; break;
        case 3:  if (ln) dv[3]  = val; break;
        case 4:  if (ln) dv[4]  = val; break;
        case 5:  if (ln) dv[5]  = val; break;
        case 6:  if (ln) dv[6]  = val; break;
        case 7:  if (ln) dv[7]  = val; break;
        case 8:  if (ln) dv[8]  = val; break;
        case 9:  if (ln) dv[9]  = val; break;
        case 10: if (ln) dv[10] = val; break;
        case 11: if (ln) dv[11] = val; break;
        case 12: if (ln) dv[12] = val; break;
        case 13: if (ln) dv[13] = val; break;
        case 14: if (ln) dv[14] = val; break;
        case 15: if (ln) dv[15] = val; break;
    }
}

__global__ __launch_bounds__(1024) void pool_merge_kernel(
    const float* __restrict__ x, float* __restrict__ out, float* vals_base) {
    const int b    = blockIdx.x;
    const int tid  = threadIdx.x;
    const int lane = tid & 63;
    const int wave = tid >> 6;

    float* vals = vals_base + (size_t)b * S * D;
    const float* xin = x + (size_t)b * S * D;

    __shared__ int4  links[S];     // {prv, nxt, nxt2, pad}; nxt2 = nxt[nxt[s]] (clamped to S)
    __shared__ float sdist[S];     // init-time dist staging (main loop keeps dist in regs)
    __shared__ int   outIdx[NCOMP];

    // ---- init: copy sample into workspace (skip if operating in place) ----
    if (vals != (float*)xin) {
        const float4* s4 = (const float4*)xin;
        float4* d4 = (float4*)vals;
        for (int i = tid; i < S * D / 4; i += 1024) d4[i] = s4[i];
    }
    for (int s = tid; s < S; s += 1024)
        links[s] = make_int4(s - 1, s + 1, (s + 2 <= S) ? s + 2 : S, 0);
    __syncthreads();

    // ---- init: 1023 adjacent-pair dots, one wave per pair ----
    for (int pr = wave; pr < S - 1; pr += NW) {
        const float4* a4 = (const float4*)(vals + (size_t)pr * D);
        const float4* b4 = (const float4*)(vals + (size_t)(pr + 1) * D);
        float4 a0 = a4[lane * 2], a1 = a4[lane * 2 + 1];
        float4 b0 = b4[lane * 2], b1 = b4[lane * 2 + 1];
        float tot = wave_sum63(dot8_partial(a0, a1, b0, b1));
        if (lane == 63) sdist[pr] = tot;
    }
    if (tid == 0) sdist[S - 1] = NEG_INF;
    __syncthreads();

    // ---- main loop: wave 0 only, barrier-free ----
    if (wave == 0) {
        float dv[16];
#pragma unroll
        for (int k = 0; k < 16; ++k) dv[k] = sdist[lane + 64 * k];  // slot = lane + 64k

        for (int t = 0; t < STEPS; ++t) {
            // local argmax over 16 regs, tree, tie -> smaller k (= smaller slot)
            float v8[8]; int k8[8];
#pragma unroll
            for (int k = 0; k < 8; ++k) { bool tk = dv[k+8] > dv[k]; v8[k] = tk ? dv[k+8] : dv[k]; k8[k] = tk ? (k+8) : k; }
            float v4[4]; int k4[4];
#pragma unroll
            for (int k = 0; k < 4; ++k) { bool tk = v8[k+4] > v8[k]; v4[k] = tk ? v8[k+4] : v8[k]; k4[k] = tk ? k8[k+4] : k8[k]; }
            float v2[2]; int k2[2];
#pragma unroll
            for (int k = 0; k < 2; ++k) { bool tk = v4[k+2] > v4[k]; v2[k] = tk ? v4[k+2] : v4[k]; k2[k] = tk ? k4[k+2] : k4[k]; }
            bool tk1 = v2[1] > v2[0];
            float lv = tk1 ? v2[1] : v2[0];
            int   lk = tk1 ? k2[1] : k2[0];

            // cross-lane argmax via DPP on a monotone uint key; min slot on ties
            unsigned key = fkey(lv);
            int bi = lane | (lk << 6);
            AMAX_STEP(0x111, 0xF); AMAX_STEP(0x112, 0xF);
            AMAX_STEP(0x114, 0xF); AMAX_STEP(0x118, 0xF);
            AMAX_STEP(0x142, 0xA); AMAX_STEP(0x143, 0xC);
            const int m = __builtin_amdgcn_readlane(bi, 63);   // uniform

            // one LDS round-trip gives p, r, q
            int4 L = links[m];
            const int p = __builtin_amdgcn_readfirstlane(L.x);
            const int r = __builtin_amdgcn_readfirstlane(L.y);
            const int q = __builtin_amdgcn_readfirstlane(L.z);
            const bool hasp = (p >= 0), hasq = (q < S);

            // row loads (L2-resident), 8 floats/lane each
            const float4* pm = (const float4*)(vals + (size_t)m * D);
            const float4* pr4 = (const float4*)(vals + (size_t)r * D);
            float4 am0 = pm[lane * 2],  am1 = pm[lane * 2 + 1];
            float4 ar0 = pr4[lane * 2], ar1 = pr4[lane * 2 + 1];
            float4 ap0, ap1, aq0, aq1;
            if (hasp) { const float4* pp = (const float4*)(vals + (size_t)p * D); ap0 = pp[lane * 2]; ap1 = pp[lane * 2 + 1]; }
            if (hasq) { const float4* pq = (const float4*)(vals + (size_t)q * D); aq0 = pq[lane * 2]; aq1 = pq[lane * 2 + 1]; }

            int n2r = __builtin_amdgcn_readfirstlane(links[r].z);  // = nxt[q], for links[m].nxt2

            // merge: vals[m] = (vals[m] + vals[r]) * 0.5
            float4 vm0, vm1;
            vm0.x = (am0.x + ar0.x) * 0.5f; vm0.y = (am0.y + ar0.y) * 0.5f;
            vm0.z = (am0.z + ar0.z) * 0.5f; vm0.w = (am0.w + ar0.w) * 0.5f;
            vm1.x = (am1.x + ar1.x) * 0.5f; vm1.y = (am1.y + ar1.y) * 0.5f;
            vm1.z = (am1.z + ar1.z) * 0.5f; vm1.w = (am1.w + ar1.w) * 0.5f;
            ((float4*)(vals + (size_t)m * D))[lane * 2]     = vm0;
            ((float4*)(vals + (size_t)m * D))[lane * 2 + 1] = vm1;

            // link maintenance (invariant: nxt2[s] == nxt[nxt[s]], clamped to S)
            if (lane == 0) {
                links[m].y = q;
                links[m].z = n2r;
                if (hasp) links[p].z = q;
                if (hasq) links[q].x = m;
            }

            // only the two dists adjacent to the merge change
            float ndm = NEG_INF, ndp = 0.0f;
            if (hasq) {
                float s_ = wave_sum63(dot8_partial(vm0, vm1, aq0, aq1));
                ndm = i2f(__builtin_amdgcn_readlane(f2i(s_), 63));
            }
            if (hasp) {
                float s_ = wave_sum63(dot8_partial(ap0, ap1, vm0, vm1));
                ndp = i2f(__builtin_amdgcn_readlane(f2i(s_), 63));
            }
            dist_set(dv, lane == (r & 63), r >> 6, NEG_INF);
            dist_set(dv, lane == (m & 63), m >> 6, ndm);
            if (hasp) dist_set(dv, lane == (p & 63), p >> 6, ndp);
        }
    }
    __syncthreads();

    // ---- output: first NCOMP active slots in list order ----
    if (tid == 0) {
        int s = 0;  // slot 0 is never removed (never a right token)
        for (int i = 0; i < NCOMP; ++i) { outIdx[i] = s; s = links[s].y; }
    }
    __syncthreads();

    float* outb = out + (size_t)b * NCOMP * D;
    for (int i = wave; i < NCOMP; i += NW) {
        const float4* sr = (const float4*)(vals + (size_t)outIdx[i] * D);
        float4* dr = (float4*)(outb + (size_t)i * D);
        dr[lane * 2]     = sr[lane * 2];
        dr[lane * 2 + 1] = sr[lane * 2 + 1];
    }
}

extern "C" void kernel_launch(void* const* d_in, const int* in_sizes, int n_in,
                              void* d_out, int out_size, void* d_ws, size_t ws_size,
                              hipStream_t stream) {
    const float* x = (const float*)d_in[0];
    float* out = (float*)d_out;
    const int b = in_sizes[0] / (S * D);   // 4
    const size_t need = (size_t)in_sizes[0] * sizeof(float);
    float* vals = (ws_size >= need) ? (float*)d_ws : (float*)x;
    pool_merge_kernel<<<dim3(b), dim3(1024), 0, stream>>>(x, out, vals);
}

// Round 3
// 1051.597 us; speedup vs baseline: 1.1970x; 1.0463x over previous
//
#include <hip/hip_runtime.h>
#include <math.h>

// Problem constants (from reference: B=4, S=1024, D=512, COMP=4)
#define S 1024
#define D 512
#define NCOMP (S / 4)        // 256
#define STEPS (S - NCOMP)    // 768
#define NEG_INF (-__builtin_inff())

__device__ __forceinline__ int   f2i(float x) { return __builtin_bit_cast(int, x); }
__device__ __forceinline__ float i2f(int x)   { return __builtin_bit_cast(float, x); }

// Monotone float->uint key (strictly >0 for any non-NaN float).
__device__ __forceinline__ unsigned fkey(float f) {
    unsigned u = __builtin_bit_cast(unsigned, f);
    return (u & 0x80000000u) ? ~u : (u | 0x80000000u);
}
__device__ __forceinline__ float unfkey(unsigned k) {
    unsigned u = (k & 0x80000000u) ? (k & 0x7fffffffu) : ~k;
    return __builtin_bit_cast(float, u);
}

// Full-wave sum via DPP; total lands in lane 63. Same order as rounds 1-2.
__device__ __forceinline__ float wave_sum63(float x) {
    x += i2f(__builtin_amdgcn_update_dpp(0, f2i(x), 0x111, 0xF, 0xF, true));
    x += i2f(__builtin_amdgcn_update_dpp(0, f2i(x), 0x112, 0xF, 0xF, true));
    x += i2f(__builtin_amdgcn_update_dpp(0, f2i(x), 0x114, 0xF, 0xF, true));
    x += i2f(__builtin_amdgcn_update_dpp(0, f2i(x), 0x118, 0xF, 0xF, true));
    x += i2f(__builtin_amdgcn_update_dpp(0, f2i(x), 0x142, 0xA, 0xF, true));
    x += i2f(__builtin_amdgcn_update_dpp(0, f2i(x), 0x143, 0xC, 0xF, true));
    return x;
}

#define AMAX_STEP(ctrl, rm) do {                                                        \
    unsigned ok_ = (unsigned)__builtin_amdgcn_update_dpp((int)key, (int)key, (ctrl), (rm), 0xF, false); \
    int      oi_ = __builtin_amdgcn_update_dpp(bi, bi, (ctrl), (rm), 0xF, false);        \
    bool tk_ = (ok_ > key) || ((ok_ == key) && (oi_ < bi));                              \
    key = tk_ ? ok_ : key; bi = tk_ ? oi_ : bi;                                          \
} while (0)

struct Row { float4 a, b; };

__device__ __forceinline__ Row row_load(const float* vals, int slot, int lane) {
    const float4* p = (const float4*)(vals + (size_t)slot * D);
    Row r; r.a = p[lane * 2]; r.b = p[lane * 2 + 1]; return r;
}
__device__ __forceinline__ void row_store(float* vals, int slot, int lane, Row r) {
    float4* p = (float4*)(vals + (size_t)slot * D);
    p[lane * 2] = r.a; p[lane * 2 + 1] = r.b;
}
__device__ __forceinline__ Row row_avg(Row x, Row y) {
    Row r;
    r.a.x = (x.a.x + y.a.x) * 0.5f; r.a.y = (x.a.y + y.a.y) * 0.5f;
    r.a.z = (x.a.z + y.a.z) * 0.5f; r.a.w = (x.a.w + y.a.w) * 0.5f;
    r.b.x = (x.b.x + y.b.x) * 0.5f; r.b.y = (x.b.y + y.b.y) * 0.5f;
    r.b.z = (x.b.z + y.b.z) * 0.5f; r.b.w = (x.b.w + y.b.w) * 0.5f;
    return r;
}
// Fixed accumulation order (identical to rounds 1-2 dot8_partial).
__device__ __forceinline__ float dot8_partial(Row x, Row y) {
    float acc = x.a.x * y.a.x;
    acc += x.a.y * y.a.y; acc += x.a.z * y.a.z; acc += x.a.w * y.a.w;
    acc += x.b.x * y.b.x; acc += x.b.y * y.b.y; acc += x.b.z * y.b.z; acc += x.b.w * y.b.w;
    return acc;
}
// clamp a slot id for a harmless row load (invalid -> row 0, never used)
__device__ __forceinline__ int lsr(int s) { return ((unsigned)s < (unsigned)S) ? s : 0; }
// clamp for links[] reads (array size S+1)
__device__ __forceinline__ int lsl(int s) { return ((unsigned)s <= (unsigned)S) ? s : 0; }

// LDS argmax: slot layout s = lane + 64k, ties -> smallest slot.
__device__ __forceinline__ void lds_argmax(const float* dist, int lane, float& v1, int& i1) {
    float av[16];
#pragma unroll
    for (int k = 0; k < 16; ++k) av[k] = dist[lane + 64 * k];
    float v8[8]; int k8[8];
#pragma unroll
    for (int k = 0; k < 8; ++k) { bool tk = av[k+8] > av[k]; v8[k] = tk ? av[k+8] : av[k]; k8[k] = tk ? (k+8) : k; }
    float v4[4]; int k4[4];
#pragma unroll
    for (int k = 0; k < 4; ++k) { bool tk = v8[k+4] > v8[k]; v4[k] = tk ? v8[k+4] : v8[k]; k4[k] = tk ? k8[k+4] : k8[k]; }
    float v2[2]; int k2[2];
#pragma unroll
    for (int k = 0; k < 2; ++k) { bool tk = v4[k+2] > v4[k]; v2[k] = tk ? v4[k+2] : v4[k]; k2[k] = tk ? k4[k+2] : k4[k]; }
    bool tk1 = v2[1] > v2[0];
    float lv = tk1 ? v2[1] : v2[0];
    int   lk = tk1 ? k2[1] : k2[0];
    unsigned key = fkey(lv);
    int bi = lane | (lk << 6);
    AMAX_STEP(0x111, 0xF); AMAX_STEP(0x112, 0xF);
    AMAX_STEP(0x114, 0xF); AMAX_STEP(0x118, 0xF);
    AMAX_STEP(0x142, 0xA); AMAX_STEP(0x143, 0xC);
    i1 = __builtin_amdgcn_readlane(bi, 63);
    v1 = unfkey((unsigned)__builtin_amdgcn_readlane((int)key, 63));
}

// ---- K1: copy x->vals (if needed) + all 1023 initial pair dots into aux ----
__global__ __launch_bounds__(256) void init_kernel(const float* __restrict__ x,
                                                   float* __restrict__ vals,
                                                   float* __restrict__ out) {
    const int blk = blockIdx.x, b = blk >> 4, g = blk & 15;
    const int tid = threadIdx.x, lane = tid & 63, w = tid >> 6;
    const float* xb = x + (size_t)b * S * D;
    if (vals != x) {
        float* vb = vals + (size_t)b * S * D;
        const float4* s4 = (const float4*)xb;
        float4* d4 = (float4*)vb;
        const int base = g * (S * D / 4 / 16);
        for (int i = tid; i < S * D / 4 / 16; i += 256) d4[base + i] = s4[base + i];
    }
    float* sd = out + (size_t)b * NCOMP * D;   // sdist staged in out chunk b
#pragma unroll 1
    for (int j = 0; j < 16; ++j) {
        int pr = g * 64 + w * 16 + j;
        if (pr < S - 1) {
            Row A = row_load(xb, pr, lane);
            Row B = row_load(xb, pr + 1, lane);
            float t = wave_sum63(dot8_partial(A, B));
            if (lane == 63) sd[pr] = t;
        }
    }
    if (g == 0 && tid == 0) sd[S - 1] = NEG_INF;
}

// ---- K2: the serial merge loop — one 64-lane wave per sample ----
__global__ __launch_bounds__(64) void merge_kernel(float* __restrict__ vals,
                                                   float* __restrict__ out) {
    const int b = blockIdx.x, lane = threadIdx.x;
    float* vb = vals + (size_t)b * S * D;
    float* aux = out + (size_t)b * NCOMP * D;
    const float* sd = aux;
    int* outIdx = (int*)(aux + S);

    __shared__ int4  links[S + 1];   // {prv, nxt, nxt2(clamped to S), pad}
    __shared__ float dist[S];

#pragma unroll
    for (int k = 0; k < 16; ++k) {
        int s = lane + 64 * k;
        links[s] = make_int4(s - 1, s + 1, (s + 2 <= S) ? (s + 2) : S, 0);
        dist[s] = sd[s];
    }
    if (lane == 0) links[S] = make_int4(S, S, S, 0);

    // first argmax (full)
    float v1; int i1;
    lds_argmax(dist, lane, v1, i1);
    int m = i1;
    int4 L0 = links[m];
    int p = __builtin_amdgcn_readfirstlane(L0.x);
    int r = __builtin_amdgcn_readfirstlane(L0.y);
    int q = __builtin_amdgcn_readfirstlane(L0.z);   // nxt2[m] == nxt[r]
    bool hasp = (p >= 0), hasq = (q < S);
    int pp = hasp ? __builtin_amdgcn_readfirstlane(links[p].x) : -1;
    int nq = hasq ? __builtin_amdgcn_readfirstlane(links[q].y) : S;
    Row Rp  = row_load(vb, lsr(p),  lane);
    Row Rm  = row_load(vb, m,       lane);
    Row Rr  = row_load(vb, r,       lane);
    Row Rq  = row_load(vb, lsr(q),  lane);
    Row Rpp = row_load(vb, lsr(pp), lane);
    Row Rnq = row_load(vb, lsr(nq), lane);

#pragma unroll 1
    for (int t = 0; t < STEPS; ++t) {
        // 1. link maintenance + dist poison (argmax exclusion of {p,m,r})
        if (lane == 0) {
            links[m].y = q; links[m].z = nq;
            if (hasp) links[p].z = q;
            if (hasq) links[q].x = m;
            dist[m] = NEG_INF; dist[r] = NEG_INF;
            if (hasp) dist[p] = NEG_INF;
        }
        // 2. merge value + store
        Row vm = row_avg(Rm, Rr);
        row_store(vb, m, lane, vm);
        if (t + 1 >= STEPS) break;

        // 3. dots for the two changed dists (rows already in registers)
        float sp_ = wave_sum63(dot8_partial(Rp, vm));
        float sq_ = wave_sum63(dot8_partial(vm, Rq));
        float ndp = hasp ? i2f(__builtin_amdgcn_readlane(f2i(sp_), 63)) : NEG_INF;
        float ndm = hasq ? i2f(__builtin_amdgcn_readlane(f2i(sq_), 63)) : NEG_INF;

        // 4. masked argmax (excludes poisoned {p,m,r}); independent of the dots
        lds_argmax(dist, lane, v1, i1);

        // 5. fixup: exact argmax = best of (v1,i1), (ndp,p), (ndm,m)
        float best = v1; int bi = i1;
        if (hasp && (ndp > best || (ndp == best && p < bi))) { best = ndp; bi = p; }
        if (hasq && (ndm > best || (ndm == best && m < bi))) { best = ndm; bi = m; }
        const int m2 = bi;

        // 6. restore true dist values
        if (lane == 0) {
            if (hasp) dist[p] = ndp;
            if (hasq) dist[m] = ndm;
        }

        // 7. speculative state for the i1 case (post-maintenance links)
        int4 Li = links[lsl(i1)];
        int p2 = __builtin_amdgcn_readfirstlane(Li.x);
        int r2 = __builtin_amdgcn_readfirstlane(Li.y);
        int q2 = __builtin_amdgcn_readfirstlane(Li.z);
        int4 Lp2 = links[lsl(p2)];
        int4 Lq2 = links[lsl(q2)];
        int pp2 = (p2 >= 0) ? __builtin_amdgcn_readfirstlane(Lp2.x) : -1;
        int nq2 = (q2 < S)  ? __builtin_amdgcn_readfirstlane(Lq2.y) : S;
        // rows (substitute vm for slot m — its fresh value lives in registers)
        Row Sp  = (p2 == m)  ? vm : row_load(vb, lsr(p2),  lane);
        Row Si  = row_load(vb, lsr(i1), lane);
        Row Sr  = row_load(vb, lsr(r2), lane);
        Row Sq  = (q2 == m)  ? vm : row_load(vb, lsr(q2),  lane);
        Row Spp = (pp2 == m) ? vm : row_load(vb, lsr(pp2), lane);
        Row Snq = (nq2 == m) ? vm : row_load(vb, lsr(nq2), lane);

        // 8. advance state (all branches leave rows for (pp,p,m,r,q,nq) in regs)
        if (m2 == m) {            // next pair (m, q)
            int nnq = S;
            if (nq < S) nnq = __builtin_amdgcn_readfirstlane(links[nq].y);
            Row Rnq2 = (nnq < S) ? row_load(vb, lsr(nnq), lane) : Rnq;
            Rm = vm; Rr = Rq; Rq = Rnq; Rnq = Rnq2;
            r = q; q = nq; nq = nnq;
            hasq = (q < S);
        } else if (m2 == p) {     // next pair (p, m)
            int npp = -1;
            if (pp >= 0) npp = __builtin_amdgcn_readfirstlane(links[pp].x);
            Row Rpp2 = (npp >= 0) ? row_load(vb, lsr(npp), lane) : Rpp;
            Rr = vm; Rm = Rp; Rp = Rpp; Rpp = Rpp2;
            r = m; m = p; p = pp; pp = npp;
            hasp = (p >= 0);
        } else {                  // next pair (i1, nxt[i1]) — speculated
            m = i1; p = p2; r = r2; q = q2; pp = pp2; nq = nq2;
            Rm = Si; Rr = Sr; Rp = Sp; Rq = Sq; Rpp = Spp; Rnq = Snq;
            hasp = (p >= 0); hasq = (q < S);
        }
    }

    // output order: walk the list from slot 0 (never removed), 2 per LDS read
    if (lane == 0) {
        int s = 0;
        for (int i = 0; i < NCOMP; i += 2) {
            outIdx[i] = s;
            int4 Ls = links[s];
            if (i + 1 < NCOMP) outIdx[i + 1] = Ls.y;
            s = Ls.z;
        }
    }
}

// ---- K3: gather the first NCOMP surviving rows into out ----
__global__ __launch_bounds__(256) void gather_kernel(const float* __restrict__ vals,
                                                     float* __restrict__ out) {
    const int b = blockIdx.x, part = blockIdx.y;
    const float* vb = vals + (size_t)b * S * D;
    float* ob = out + (size_t)b * NCOMP * D;
    __shared__ int oi[NCOMP / 8];
    const int row0 = part * (NCOMP / 8);
    if (threadIdx.x < NCOMP / 8)
        oi[threadIdx.x] = ((const int*)(ob + S))[row0 + threadIdx.x];
    __syncthreads();
    const float4* v4 = (const float4*)vb;
    float4* o4 = (float4*)ob;
    const int per = (NCOMP / 8) * (D / 4);            // 4096 float4s per part
    for (int idx = threadIdx.x; idx < per; idx += 256) {
        int row = idx >> 7, c = idx & 127;
        o4[(size_t)(row0 + row) * (D / 4) + c] = v4[(size_t)oi[row] * (D / 4) + c];
    }
}

extern "C" void kernel_launch(void* const* d_in, const int* in_sizes, int n_in,
                              void* d_out, int out_size, void* d_ws, size_t ws_size,
                              hipStream_t stream) {
    const float* x = (const float*)d_in[0];
    float* out = (float*)d_out;
    const int b = in_sizes[0] / (S * D);   // 4
    const size_t need = (size_t)in_sizes[0] * sizeof(float);
    float* vals = (ws_size >= need) ? (float*)d_ws : (float*)x;
    init_kernel<<<dim3(16 * b), dim3(256), 0, stream>>>(x, vals, out);
    merge_kernel<<<dim3(b), dim3(64), 0, stream>>>(vals, out);
    gather_kernel<<<dim3(b, 8), dim3(256), 0, stream>>>(vals, out);
}